// Round 11
// baseline (254.135 us; speedup 1.0000x reference)
//
#include <hip/hip_runtime.h>

typedef __bf16 bf16x8 __attribute__((ext_vector_type(8)));
typedef float f32x4 __attribute__((ext_vector_type(4)));
typedef float f32x16 __attribute__((ext_vector_type(16)));

#define NROWS 4096   // B*T
#define DM 2048
#define LAT 512
#define NH 16
#define DH 128

__device__ __forceinline__ unsigned short f2bf(float f) {
    union { float f; unsigned u; } v; v.f = f;
    unsigned r = v.u + 0x7fffu + ((v.u >> 16) & 1u);
    return (unsigned short)(r >> 16);
}
__device__ __forceinline__ void gload16(const void* g, void* l) {
    __builtin_amdgcn_global_load_lds((const __attribute__((address_space(1))) unsigned int*)g,
                                     (__attribute__((address_space(3))) unsigned int*)l, 16, 0, 0);
}
__device__ __forceinline__ unsigned cvtpk_bf16(float lo, float hi) {
    unsigned r;
    asm("v_cvt_pk_bf16_f32 %0, %1, %2" : "=v"(r) : "v"(lo), "v"(hi));
    return r;
}
__device__ __forceinline__ void pl32swap(unsigned& a, unsigned& b) {
    asm("v_permlane32_swap_b32 %0, %1" : "+v"(a), "+v"(b));
}
// raw v_exp_f32 (2^x) — avoids __ocml_exp2_f32's denormal fixup (R4 regression)
__device__ __forceinline__ float exp2a(float x) {
    float r;
    asm("v_exp_f32 %0, %1" : "=v"(r) : "v"(x));
    return r;
}

// ---------- consolidated prep: 8 weight transposes + x->bf16 + rope table + bias concat ----------
struct PrepParams {
    const float* tsrc[8]; unsigned short* tdst[8];
    int tK[8]; int tN[8]; int tstart[8];
    const float* input; unsigned short* xbf;
    float* cs; float* sn;
    const float* bsrc[8]; float* bdst[8]; int blen[8];
};

#define PREP_T_END   9984
#define PREP_X_END   18176
#define PREP_R_END   18304
#define PREP_B_END   18340

__global__ __launch_bounds__(256) void prep_kernel(PrepParams P) {
    const int bid = blockIdx.x, tid = threadIdx.x;
    if (bid < PREP_T_END) {
        int j = 0;
        #pragma unroll
        for (int i = 1; i < 8; ++i) if (bid >= P.tstart[i]) j = i;
        const int local = bid - P.tstart[j];
        const float* W = P.tsrc[j];
        unsigned short* Wt = P.tdst[j];
        const int K = P.tK[j], N = P.tN[j];
        const int nbx = N >> 5;
        const int nb = (local % nbx) * 32, kb = (local / nbx) * 32;
        __shared__ float tile[32][33];
        const int tx = tid & 31, ty = tid >> 5;
        #pragma unroll
        for (int i = 0; i < 32; i += 8)
            tile[ty + i][tx] = W[(size_t)(kb + ty + i) * N + nb + tx];
        __syncthreads();
        #pragma unroll
        for (int i = 0; i < 32; i += 8)
            Wt[(size_t)(nb + ty + i) * K + kb + tx] = f2bf(tile[tx][ty + i]);
    } else if (bid < PREP_X_END) {
        const int i = ((bid - PREP_T_END) * 256 + tid) * 4;
        float4 v = *(const float4*)(P.input + i);
        unsigned short* y = P.xbf + i;
        y[0] = f2bf(v.x); y[1] = f2bf(v.y); y[2] = f2bf(v.z); y[3] = f2bf(v.w);
    } else if (bid < PREP_R_END) {
        const int idx = (bid - PREP_X_END) * 256 + tid;
        const int i = idx & 15, t = idx >> 4;
        float inv = powf(10000.0f, -(float)i / 16.0f);
        float a = (float)t * inv;
        P.cs[idx] = cosf(a);
        P.sn[idx] = sinf(a);
    } else {
        const int gid = (bid - PREP_R_END) * 256 + tid;
        int off = 0;
        #pragma unroll
        for (int i = 0; i < 8; ++i) {
            if (gid >= off && gid < off + P.blen[i])
                P.bdst[i][gid - off] = P.bsrc[i][gid - off];
            off += P.blen[i];
        }
    }
}

// ---------- fused bf16 GEMM, BK-templated ----------
// which=0 (G1, K=2048, BK=64, grid 32x12): by<4 c_kv(f32+bf16); by<8 c_q; else k_rot RoPE
// which=1 (G2+G3 merged, K=512, BK=32, grid 32x44): by<12 k_base remap(outB0);
//         12<=by<28 V^T bounce(outB1); 28<=by<40 q_base remap(outB0k); else q_rot RoPE(outB0k)
//         A for by<28, A2 for by>=28
// which=3 (G4, K=2048, BK=64, grid 32x16): outF = final output (f32)
template<int BK>
__global__ __launch_bounds__(256) void gemm_fused_kernel(const unsigned short* __restrict__ A,
                                                         const unsigned short* __restrict__ A2,
                                                         const unsigned short* __restrict__ Bt,
                                                         const float* __restrict__ biascat,
                                                         int K, int which,
                                                         float* __restrict__ outF,
                                                         unsigned short* __restrict__ outB0,
                                                         unsigned short* __restrict__ outB1,
                                                         unsigned short* __restrict__ outB0k,
                                                         float* __restrict__ outRope,
                                                         const float* __restrict__ cs,
                                                         const float* __restrict__ sn) {
    constexpr int RPC = 512 / BK;            // rows per 1KB staging chunk
    constexpr int NCHA = BK / 4;             // chunks per matrix (A or B)
    __shared__ __align__(16) unsigned short SM[2][256 * BK];   // A(128*BK) | B(128*BK)
    const int tid = threadIdx.x;
    const int mb = blockIdx.x * 128;
    const int by = blockIdx.y, nb = by * 128;
    const int w = tid >> 6, lane = tid & 63;
    const int wr = (w >> 1) * 64, wc = (w & 1) * 64;
    const int l15 = lane & 15, l4 = lane >> 4;
    const int srow = lane / (BK / 8), sko = (lane % (BK / 8)) * 8;

    const unsigned short* Ause = (which == 1 && by >= 28) ? A2 : A;

    f32x4 acc[4][4] = {};

    auto STAGE = [&](int buf, int k0) {
        #pragma unroll
        for (int c = 0; c < 2 * NCHA; c += 4) {
            int cc = c + w;
            if (cc < NCHA)
                gload16(Ause + (size_t)(mb + cc * RPC + srow) * K + k0 + sko, SM[buf] + cc * 512);
            else
                gload16(Bt + (size_t)(nb + (cc - NCHA) * RPC + srow) * K + k0 + sko,
                        SM[buf] + 128 * BK + (cc - NCHA) * 512);
        }
    };

    const int nk = K / BK;
    STAGE(0, 0);
    for (int kt = 0; kt < nk; ++kt) {
        const int buf = kt & 1;
        if (kt + 1 < nk) {
            STAGE(buf ^ 1, (kt + 1) * BK);
            if constexpr (BK == 32) asm volatile("s_waitcnt vmcnt(4)" ::: "memory");
            else                    asm volatile("s_waitcnt vmcnt(8)" ::: "memory");
        } else {
            asm volatile("s_waitcnt vmcnt(0)" ::: "memory");
        }
        __builtin_amdgcn_sched_barrier(0);
        __builtin_amdgcn_s_barrier();
        __builtin_amdgcn_sched_barrier(0);

        const unsigned short* As = SM[buf];
        const unsigned short* Bs = SM[buf] + 128 * BK;
        #pragma unroll
        for (int kk = 0; kk < BK; kk += 32) {
            bf16x8 af[4], bfr[4];
            #pragma unroll
            for (int mi = 0; mi < 4; ++mi)
                af[mi] = *(const bf16x8*)(As + (wr + mi * 16 + l15) * BK + kk + l4 * 8);
            #pragma unroll
            for (int ni = 0; ni < 4; ++ni)
                bfr[ni] = *(const bf16x8*)(Bs + (wc + ni * 16 + l15) * BK + kk + l4 * 8);
            #pragma unroll
            for (int mi = 0; mi < 4; ++mi)
                #pragma unroll
                for (int ni = 0; ni < 4; ++ni)
                    acc[mi][ni] = __builtin_amdgcn_mfma_f32_16x16x32_bf16(af[mi], bfr[ni], acc[mi][ni], 0, 0, 0);
        }
        __builtin_amdgcn_s_barrier();
    }

    if (which == 1 && by >= 12 && by < 28) {
        // ---- V^T via LDS bounce: coalesced 16B stores along token dim ----
        unsigned short* BT = &SM[0][0];
        const int c2b = nb - 1536;
        #pragma unroll
        for (int half = 0; half < 2; ++half) {
            __syncthreads();
            if ((wr >> 6) == half) {
                #pragma unroll
                for (int mi = 0; mi < 4; ++mi)
                    #pragma unroll
                    for (int ni = 0; ni < 4; ++ni) {
                        const int col = wc + ni * 16 + l15;
                        const float bv = biascat[nb + col];
                        ushort4 pv;
                        pv.x = f2bf(acc[mi][ni][0] + bv);
                        pv.y = f2bf(acc[mi][ni][1] + bv);
                        pv.z = f2bf(acc[mi][ni][2] + bv);
                        pv.w = f2bf(acc[mi][ni][3] + bv);
                        *(ushort4*)(BT + col * 72 + mi * 16 + l4 * 4) = pv;
                    }
            }
            __syncthreads();
            const int c = tid >> 1;
            #pragma unroll
            for (int j = 0; j < 4; ++j) {
                const int seg = (tid & 1) * 4 + j;
                uint4 val = *(const uint4*)(BT + c * 72 + seg * 8);
                *(uint4*)(outB1 + (size_t)(c2b + c) * 4096 + mb + half * 64 + seg * 8) = val;
            }
        }
        return;
    }

    #pragma unroll
    for (int mi = 0; mi < 4; ++mi) {
        const int row0 = mb + wr + mi * 16 + l4 * 4;
        #pragma unroll
        for (int ni = 0; ni < 4; ++ni) {
            const int colg = nb + wc + ni * 16 + l15;
            const float bv = biascat[colg];
            float v[4];
            #pragma unroll
            for (int r = 0; r < 4; ++r) v[r] = acc[mi][ni][r] + bv;

            if (which == 0) {
                if (by < 4) {
                    #pragma unroll
                    for (int r = 0; r < 4; ++r) {
                        outF[(size_t)(row0 + r) * 512 + colg] = v[r];
                        outB0[(size_t)(row0 + r) * 512 + colg] = f2bf(v[r]);
                    }
                } else if (by < 8) {
                    const int c2 = colg - 512;
                    #pragma unroll
                    for (int r = 0; r < 4; ++r)
                        outB1[(size_t)(row0 + r) * 512 + c2] = f2bf(v[r]);
                } else {
                    const int cloc = colg - 1024, i2 = cloc & 31, h2 = cloc >> 5;
                    const float pbv = biascat[colg ^ 16];
                    const bool lo = (ni & 1) == 0;
                    #pragma unroll
                    for (int r = 0; r < 4; ++r) {
                        float vp = acc[mi][ni ^ 1][r] + pbv;
                        int t = (row0 + r) & 2047;
                        float cc_ = cs[t * 16 + (i2 & 15)], ss_ = sn[t * 16 + (i2 & 15)];
                        float o = lo ? (v[r] * cc_ - vp * ss_) : (v[r] * cc_ + vp * ss_);
                        outRope[(size_t)(row0 + r) * 512 + cloc] = o;
                        outB0k[(size_t)(row0 + r) * 2048 + h2 * 128 + 96 + i2] = f2bf(o);
                    }
                }
            } else if (which == 1) {
                if (by < 12) {
                    const int ocol = (colg / 96) * 128 + colg % 96;
                    #pragma unroll
                    for (int r = 0; r < 4; ++r)
                        outB0[(size_t)(row0 + r) * 2048 + ocol] = f2bf(v[r]);
                } else if (by < 40) {
                    const int c3 = colg - 3584;
                    const int ocol = (c3 / 96) * 128 + c3 % 96;
                    #pragma unroll
                    for (int r = 0; r < 4; ++r)
                        outB0k[(size_t)(row0 + r) * 2048 + ocol] = f2bf(v[r]);
                } else {
                    const int cloc = colg - 5120, i2 = cloc & 31, h2 = cloc >> 5;
                    const float pbv = biascat[colg ^ 16];
                    const bool lo = (ni & 1) == 0;
                    #pragma unroll
                    for (int r = 0; r < 4; ++r) {
                        float vp = acc[mi][ni ^ 1][r] + pbv;
                        int t = (row0 + r) & 2047;
                        float cc_ = cs[t * 16 + (i2 & 15)], ss_ = sn[t * 16 + (i2 & 15)];
                        float o = lo ? (v[r] * cc_ - vp * ss_) : (v[r] * cc_ + vp * ss_);
                        outB0k[(size_t)(row0 + r) * 2048 + h2 * 128 + 96 + i2] = f2bf(o);
                    }
                }
            } else {
                #pragma unroll
                for (int r = 0; r < 4; ++r)
                    outF[(size_t)(row0 + r) * 2048 + colg] = v[r];
            }
        }
    }
}

// ---------- flash attention (R6/R10 structure, frozen) ----------
__global__ __launch_bounds__(256, 2) void attn_kernel(const unsigned short* __restrict__ Q,
                                                      const unsigned short* __restrict__ Kb,
                                                      const unsigned short* __restrict__ Vtg,
                                                      unsigned short* __restrict__ O) {
    __shared__ __align__(16) unsigned short Ks[2][64 * 128];  // [key][d ^ ((key&7)<<3)]
    __shared__ __align__(16) unsigned short Vs[2][128 * 64];  // [d][k ^ ((d&7)<<3)]

    const int tid = threadIdx.x, w = tid >> 6, lane = tid & 63;
    const int l31 = lane & 31, hi = lane >> 5;
    const int bid = blockIdx.x;
    const int logical = (bid & 7) * 64 + (bid >> 3);
    const int bh = logical >> 4, b = bh >> 4, h = bh & 15;
    const int qt = (logical & 15) * 128 + w * 32;
    const int qrow = qt + l31;
    const float sl2e = 0.08838834764831845f * 1.4426950408889634f;  // scale*log2e

    bf16x8 qf[8];
    const unsigned short* qptr = Q + (size_t)(b * 2048 + qrow) * 2048 + h * 128 + hi * 8;
    #pragma unroll
    for (int s = 0; s < 8; ++s) qf[s] = *(const bf16x8*)(qptr + s * 16);

    f32x16 acc[4] = {};
    float m_run = -1e30f, l_run = 0.0f;

    const int kl15 = lane >> 4, kd0 = lane & 15;
    const int vr = lane >> 3, vk = lane & 7;

    auto STAGE = [&](int buf, int kt) {
        #pragma unroll
        for (int i = 0; i < 4; ++i) {
            int c = w * 4 + i;
            int key = c * 4 + kl15;
            int d0 = (kd0 * 8) ^ ((key & 7) << 3);
            gload16(Kb + (size_t)(b * 2048 + kt + key) * 2048 + h * 128 + d0, &Ks[buf][c * 512]);
            int dv = c * 8 + vr;
            int k0 = (vk * 8) ^ ((dv & 7) << 3);
            gload16(Vtg + (size_t)(h * 128 + dv) * 4096 + b * 2048 + kt + k0, &Vs[buf][c * 512]);
        }
    };

    STAGE(0, 0);

    for (int t = 0; t < 32; ++t) {
        const int buf = t & 1;
        if (t < 31) {
            STAGE(buf ^ 1, (t + 1) * 64);
            asm volatile("s_waitcnt vmcnt(8)" ::: "memory");
        } else {
            asm volatile("s_waitcnt vmcnt(0)" ::: "memory");
        }
        __builtin_amdgcn_sched_barrier(0);
        __builtin_amdgcn_s_barrier();
        __builtin_amdgcn_sched_barrier(0);

        #pragma unroll
        for (int g = 0; g < 2; ++g) {
            const int key = g * 32 + l31;
            const unsigned short* kbase = &Ks[buf][key * 128];
            const int ksw = (key & 7) << 3;
            f32x16 sc = {};
            __builtin_amdgcn_s_setprio(1);
            #pragma unroll
            for (int s = 0; s < 8; ++s) {
                bf16x8 kf = *(const bf16x8*)(kbase + ((s * 16 + hi * 8) ^ ksw));
                sc = __builtin_amdgcn_mfma_f32_32x32x16_bf16(kf, qf[s], sc, 0, 0, 0);
            }
            __builtin_amdgcn_s_setprio(0);

            float t0 = fmaxf(sc[0], sc[1]),  t1 = fmaxf(sc[2], sc[3]);
            float t2 = fmaxf(sc[4], sc[5]),  t3 = fmaxf(sc[6], sc[7]);
            float t4 = fmaxf(sc[8], sc[9]),  t5 = fmaxf(sc[10], sc[11]);
            float t6 = fmaxf(sc[12], sc[13]), t7 = fmaxf(sc[14], sc[15]);
            float pm = fmaxf(fmaxf(fmaxf(t0, t1), fmaxf(t2, t3)),
                             fmaxf(fmaxf(t4, t5), fmaxf(t6, t7)));
            pm = fmaxf(pm, __shfl_xor(pm, 32, 64));

            if (__any(pm > m_run + 90.51f)) {
                float mn = fmaxf(m_run, pm);
                float f = exp2a((m_run - mn) * sl2e);
                m_run = mn;
                l_run *= f;
                #pragma unroll
                for (int dg = 0; dg < 4; ++dg)
                    #pragma unroll
                    for (int i = 0; i < 16; ++i) acc[dg][i] *= f;
            }
            const float mexp2 = m_run * sl2e;

            float e[16];
            #pragma unroll
            for (int j = 0; j < 16; ++j)
                e[j] = exp2a(fmaf(sc[j], sl2e, -mexp2));
            float a0 = e[0] + e[1], a1 = e[2] + e[3], a2 = e[4] + e[5], a3 = e[6] + e[7];
            float a4 = e[8] + e[9], a5 = e[10] + e[11], a6 = e[12] + e[13], a7 = e[14] + e[15];
            l_run += ((a0 + a1) + (a2 + a3)) + ((a4 + a5) + (a6 + a7));

            #pragma unroll
            for (int s2 = 0; s2 < 2; ++s2) {
                unsigned X0 = cvtpk_bf16(e[s2 * 8 + 0], e[s2 * 8 + 1]);
                unsigned X1 = cvtpk_bf16(e[s2 * 8 + 2], e[s2 * 8 + 3]);
                unsigned Y0 = cvtpk_bf16(e[s2 * 8 + 4], e[s2 * 8 + 5]);
                unsigned Y1 = cvtpk_bf16(e[s2 * 8 + 6], e[s2 * 8 + 7]);
                pl32swap(X0, Y0);
                pl32swap(X1, Y1);
                union { unsigned u[4]; bf16x8 v; } pf;
                pf.u[0] = X0; pf.u[1] = X1; pf.u[2] = Y0; pf.u[3] = Y1;

                const int kofs = g * 32 + s2 * 16 + hi * 8;
                __builtin_amdgcn_s_setprio(1);
                #pragma unroll
                for (int dg = 0; dg < 4; ++dg) {
                    const int d = dg * 32 + l31;
                    bf16x8 vf = *(const bf16x8*)(&Vs[buf][d * 64 + (kofs ^ ((d & 7) << 3))]);
                    acc[dg] = __builtin_amdgcn_mfma_f32_32x32x16_bf16(vf, pf.v, acc[dg], 0, 0, 0);
                }
                __builtin_amdgcn_s_setprio(0);
            }
        }
        __builtin_amdgcn_s_barrier();
    }

    l_run += __shfl_xor(l_run, 32, 64);
    const float inv = 1.0f / l_run;
    unsigned short* obase = O + (size_t)(b * 2048 + qrow) * 2048 + h * 128;
    #pragma unroll
    for (int dg = 0; dg < 4; ++dg)
        #pragma unroll
        for (int k = 0; k < 4; ++k) {
            ushort4 pv;
            pv.x = f2bf(acc[dg][4 * k + 0] * inv);
            pv.y = f2bf(acc[dg][4 * k + 1] * inv);
            pv.z = f2bf(acc[dg][4 * k + 2] * inv);
            pv.w = f2bf(acc[dg][4 * k + 3] * inv);
            *(ushort4*)(obase + dg * 32 + k * 8 + hi * 4) = pv;
        }
}

extern "C" void kernel_launch(void* const* d_in, const int* in_sizes, int n_in,
                              void* d_out, int out_size, void* d_ws, size_t ws_size,
                              hipStream_t stream) {
    (void)in_sizes; (void)n_in; (void)out_size; (void)ws_size;

    const float* input  = (const float*)d_in[0];
    const float* Wdkv_w = (const float*)d_in[3];
    const float* Wdkv_b = (const float*)d_in[4];
    const float* Wdq_w  = (const float*)d_in[5];
    const float* Wdq_b  = (const float*)d_in[6];
    const float* Wuk_w  = (const float*)d_in[7];
    const float* Wuk_b  = (const float*)d_in[8];
    const float* Wuv_w  = (const float*)d_in[9];
    const float* Wuv_b  = (const float*)d_in[10];
    const float* Wuq_w  = (const float*)d_in[11];
    const float* Wuq_b  = (const float*)d_in[12];
    const float* Wqr_w  = (const float*)d_in[13];
    const float* Wqr_b  = (const float*)d_in[14];
    const float* Wkr_w  = (const float*)d_in[15];
    const float* Wkr_b  = (const float*)d_in[16];
    const float* Wo_w   = (const float*)d_in[17];
    const float* Wo_b   = (const float*)d_in[18];

    float* out_main = (float*)d_out;                       // [4096][2048]
    float* out_ckv  = out_main + (size_t)NROWS * DM;       // [4096][512]
    float* out_krot = out_ckv + (size_t)NROWS * LAT;       // [4096][512]

    char* p = (char*)d_ws;
    auto alloc = [&](size_t bytes) { char* r = p; p += (bytes + 255) & ~(size_t)255; return r; };
    unsigned short* x_bf  = (unsigned short*)alloc((size_t)NROWS * DM * 2);
    unsigned short* w1_t  = (unsigned short*)alloc((size_t)1536 * DM * 2);   // [dkv|dq|kr] x 2048
    unsigned short* w23_t = (unsigned short*)alloc((size_t)5632 * LAT * 2);  // [uk|uv|uq|qr] x 512
    unsigned short* w4_t  = (unsigned short*)alloc((size_t)DM * DM * 2);     // wo
    unsigned short* ckv_bf = (unsigned short*)alloc((size_t)NROWS * LAT * 2);
    unsigned short* cq_bf  = (unsigned short*)alloc((size_t)NROWS * LAT * 2);
    unsigned short* q_bf   = (unsigned short*)alloc((size_t)NROWS * DM * 2);
    unsigned short* k_bf   = (unsigned short*)alloc((size_t)NROWS * DM * 2);
    unsigned short* vt_g   = (unsigned short*)alloc((size_t)DM * NROWS * 2); // V^T [2048][4096]
    unsigned short* ao_bf  = (unsigned short*)alloc((size_t)NROWS * DM * 2);
    float* cos_t = (float*)alloc((size_t)2048 * 16 * 4);
    float* sin_t = (float*)alloc((size_t)2048 * 16 * 4);
    float* bc1  = (float*)alloc(1536 * 4);
    float* bc23 = (float*)alloc(5632 * 4);
    float* bc4  = (float*)alloc(2048 * 4);

    // ---- single prep dispatch ----
    PrepParams P;
    const float* tsrc[8] = {Wdkv_w, Wdq_w, Wkr_w, Wuk_w, Wuv_w, Wuq_w, Wqr_w, Wo_w};
    unsigned short* tdst[8] = {w1_t, w1_t + 512 * 2048, w1_t + 1024 * 2048,
                               w23_t, w23_t + 1536 * 512, w23_t + 3584 * 512, w23_t + 5120 * 512, w4_t};
    int tK[8] = {2048, 2048, 2048, 512, 512, 512, 512, 2048};
    int tN[8] = {512, 512, 512, 1536, 2048, 1536, 512, 2048};
    int tstart[8] = {0, 1024, 2048, 3072, 3840, 4864, 5632, 5888};
    const float* bsrc[8] = {Wdkv_b, Wdq_b, Wkr_b, Wuk_b, Wuv_b, Wuq_b, Wqr_b, Wo_b};
    float* bdst[8] = {bc1, bc1 + 512, bc1 + 1024, bc23, bc23 + 1536, bc23 + 3584, bc23 + 5120, bc4};
    int blen[8] = {512, 512, 512, 1536, 2048, 1536, 512, 2048};
    for (int i = 0; i < 8; ++i) {
        P.tsrc[i] = tsrc[i]; P.tdst[i] = tdst[i]; P.tK[i] = tK[i]; P.tN[i] = tN[i];
        P.tstart[i] = tstart[i]; P.bsrc[i] = bsrc[i]; P.bdst[i] = bdst[i]; P.blen[i] = blen[i];
    }
    P.input = input; P.xbf = x_bf; P.cs = cos_t; P.sn = sin_t;
    prep_kernel<<<PREP_B_END, 256, 0, stream>>>(P);

    // G1 (BK=64): x @ [Wdkv|Wdq|Wkr] -> c_kv(f32+bf16), c_q, k_rot RoPE
    gemm_fused_kernel<64><<<dim3(32, 12), 256, 0, stream>>>(x_bf, nullptr, w1_t, bc1, 2048, 0,
                                                            out_ckv, ckv_bf, cq_bf, k_bf, out_krot, cos_t, sin_t);
    // G2+G3 merged (BK=32): ckv/cq @ [uk|uv|uq|qr] -> k_base, V^T, q_base, q_rot
    gemm_fused_kernel<32><<<dim3(32, 44), 256, 0, stream>>>(ckv_bf, cq_bf, w23_t, bc23, 512, 1,
                                                            nullptr, k_bf, vt_g, q_bf, nullptr, cos_t, sin_t);

    // attention (1-D grid, XCD-swizzled; frozen R6/R10 structure)
    attn_kernel<<<512, 256, 0, stream>>>(q_bf, k_bf, vt_g, ao_bf);

    // G4 (BK=64): output projection
    gemm_fused_kernel<64><<<dim3(32, 16), 256, 0, stream>>>(ao_bf, nullptr, w4_t, bc4, 2048, 3,
                                                            out_main, nullptr, nullptr, nullptr, nullptr, nullptr, nullptr);
}

// Round 12
// 239.950 us; speedup vs baseline: 1.0591x; 1.0591x over previous
//
#include <hip/hip_runtime.h>

typedef __bf16 bf16x8 __attribute__((ext_vector_type(8)));
typedef float f32x4 __attribute__((ext_vector_type(4)));
typedef float f32x16 __attribute__((ext_vector_type(16)));

#define NROWS 4096   // B*T
#define DM 2048
#define LAT 512
#define NH 16
#define DH 128

__device__ __forceinline__ unsigned short f2bf(float f) {
    union { float f; unsigned u; } v; v.f = f;
    unsigned r = v.u + 0x7fffu + ((v.u >> 16) & 1u);
    return (unsigned short)(r >> 16);
}
__device__ __forceinline__ void gload16(const void* g, void* l) {
    __builtin_amdgcn_global_load_lds((const __attribute__((address_space(1))) unsigned int*)g,
                                     (__attribute__((address_space(3))) unsigned int*)l, 16, 0, 0);
}
__device__ __forceinline__ unsigned cvtpk_bf16(float lo, float hi) {
    unsigned r;
    asm("v_cvt_pk_bf16_f32 %0, %1, %2" : "=v"(r) : "v"(lo), "v"(hi));
    return r;
}
__device__ __forceinline__ void pl32swap(unsigned& a, unsigned& b) {
    asm("v_permlane32_swap_b32 %0, %1" : "+v"(a), "+v"(b));
}
// raw v_exp_f32 (2^x) — avoids __ocml_exp2_f32's denormal fixup (R4 regression)
__device__ __forceinline__ float exp2a(float x) {
    float r;
    asm("v_exp_f32 %0, %1" : "=v"(r) : "v"(x));
    return r;
}

// ---------- consolidated prep: 8 weight transposes + x->bf16 + rope table + bias concat ----------
struct PrepParams {
    const float* tsrc[8]; unsigned short* tdst[8];
    int tK[8]; int tN[8]; int tstart[8];
    const float* input; unsigned short* xbf;
    float* cs; float* sn;
    const float* bsrc[8]; float* bdst[8]; int blen[8];
};

#define PREP_T_END   9984
#define PREP_X_END   18176
#define PREP_R_END   18304
#define PREP_B_END   18340

__global__ __launch_bounds__(256) void prep_kernel(PrepParams P) {
    const int bid = blockIdx.x, tid = threadIdx.x;
    if (bid < PREP_T_END) {
        int j = 0;
        #pragma unroll
        for (int i = 1; i < 8; ++i) if (bid >= P.tstart[i]) j = i;
        const int local = bid - P.tstart[j];
        const float* W = P.tsrc[j];
        unsigned short* Wt = P.tdst[j];
        const int K = P.tK[j], N = P.tN[j];
        const int nbx = N >> 5;
        const int nb = (local % nbx) * 32, kb = (local / nbx) * 32;
        __shared__ float tile[32][33];
        const int tx = tid & 31, ty = tid >> 5;
        #pragma unroll
        for (int i = 0; i < 32; i += 8)
            tile[ty + i][tx] = W[(size_t)(kb + ty + i) * N + nb + tx];
        __syncthreads();
        #pragma unroll
        for (int i = 0; i < 32; i += 8)
            Wt[(size_t)(nb + ty + i) * K + kb + tx] = f2bf(tile[tx][ty + i]);
    } else if (bid < PREP_X_END) {
        const int i = ((bid - PREP_T_END) * 256 + tid) * 4;
        float4 v = *(const float4*)(P.input + i);
        unsigned short* y = P.xbf + i;
        y[0] = f2bf(v.x); y[1] = f2bf(v.y); y[2] = f2bf(v.z); y[3] = f2bf(v.w);
    } else if (bid < PREP_R_END) {
        const int idx = (bid - PREP_X_END) * 256 + tid;
        const int i = idx & 15, t = idx >> 4;
        float inv = powf(10000.0f, -(float)i / 16.0f);
        float a = (float)t * inv;
        P.cs[idx] = cosf(a);
        P.sn[idx] = sinf(a);
    } else {
        const int gid = (bid - PREP_R_END) * 256 + tid;
        int off = 0;
        #pragma unroll
        for (int i = 0; i < 8; ++i) {
            if (gid >= off && gid < off + P.blen[i])
                P.bdst[i][gid - off] = P.bsrc[i][gid - off];
            off += P.blen[i];
        }
    }
}

// ---------- fused bf16 GEMM (R6/R10 configuration — known-good) ----------
__global__ __launch_bounds__(256) void gemm_fused_kernel(const unsigned short* __restrict__ A,
                                                         const unsigned short* __restrict__ Bt,
                                                         const float* __restrict__ biascat,
                                                         int K, int which,
                                                         float* __restrict__ outF,
                                                         unsigned short* __restrict__ outB0,
                                                         unsigned short* __restrict__ outB1,
                                                         unsigned short* __restrict__ outB0k,
                                                         float* __restrict__ outRope,
                                                         const float* __restrict__ cs,
                                                         const float* __restrict__ sn) {
    __shared__ __align__(16) unsigned short SM[2][8192];
    const int tid = threadIdx.x;
    const int mb = blockIdx.x * 128;
    const int by = blockIdx.y, nb = by * 128;
    const int w = tid >> 6, lane = tid & 63;
    const int wr = (w >> 1) * 64, wc = (w & 1) * 64;
    const int l15 = lane & 15, l4 = lane >> 4;
    const int srow = lane >> 2, sko = (lane & 3) * 8;

    f32x4 acc[4][4] = {};

    auto STAGE = [&](int buf, int k0) {
        #pragma unroll
        for (int c = 0; c < 16; c += 4) {
            int cc = c + w;
            if (cc < 8)
                gload16(A + (size_t)(mb + cc * 16 + srow) * K + k0 + sko, SM[buf] + cc * 512);
            else
                gload16(Bt + (size_t)(nb + (cc - 8) * 16 + srow) * K + k0 + sko, SM[buf] + 4096 + (cc - 8) * 512);
        }
    };

    const int nk = K >> 5;
    STAGE(0, 0);
    for (int kt = 0; kt < nk; ++kt) {
        const int buf = kt & 1;
        if (kt + 1 < nk) {
            STAGE(buf ^ 1, (kt + 1) << 5);
            asm volatile("s_waitcnt vmcnt(4)" ::: "memory");
        } else {
            asm volatile("s_waitcnt vmcnt(0)" ::: "memory");
        }
        __builtin_amdgcn_sched_barrier(0);
        __builtin_amdgcn_s_barrier();
        __builtin_amdgcn_sched_barrier(0);

        const unsigned short* As = SM[buf];
        const unsigned short* Bs = SM[buf] + 4096;
        bf16x8 af[4], bfr[4];
        #pragma unroll
        for (int mi = 0; mi < 4; ++mi)
            af[mi] = *(const bf16x8*)(As + (wr + mi * 16 + l15) * 32 + l4 * 8);
        #pragma unroll
        for (int ni = 0; ni < 4; ++ni)
            bfr[ni] = *(const bf16x8*)(Bs + (wc + ni * 16 + l15) * 32 + l4 * 8);
        #pragma unroll
        for (int mi = 0; mi < 4; ++mi)
            #pragma unroll
            for (int ni = 0; ni < 4; ++ni)
                acc[mi][ni] = __builtin_amdgcn_mfma_f32_16x16x32_bf16(af[mi], bfr[ni], acc[mi][ni], 0, 0, 0);
        __builtin_amdgcn_s_barrier();
    }

    if (which == 1 && by >= 12) {
        // ---- V^T via LDS bounce: coalesced 16B stores along token dim ----
        unsigned short* BT = &SM[0][0];
        const int c2b = nb - 1536;
        #pragma unroll
        for (int half = 0; half < 2; ++half) {
            __syncthreads();
            if ((wr >> 6) == half) {
                #pragma unroll
                for (int mi = 0; mi < 4; ++mi)
                    #pragma unroll
                    for (int ni = 0; ni < 4; ++ni) {
                        const int col = wc + ni * 16 + l15;
                        const float bv = biascat[nb + col];
                        ushort4 pv;
                        pv.x = f2bf(acc[mi][ni][0] + bv);
                        pv.y = f2bf(acc[mi][ni][1] + bv);
                        pv.z = f2bf(acc[mi][ni][2] + bv);
                        pv.w = f2bf(acc[mi][ni][3] + bv);
                        *(ushort4*)(BT + col * 72 + mi * 16 + l4 * 4) = pv;
                    }
            }
            __syncthreads();
            const int c = tid >> 1;
            #pragma unroll
            for (int j = 0; j < 4; ++j) {
                const int seg = (tid & 1) * 4 + j;
                uint4 val = *(const uint4*)(BT + c * 72 + seg * 8);
                *(uint4*)(outB1 + (size_t)(c2b + c) * 4096 + mb + half * 64 + seg * 8) = val;
            }
        }
        return;
    }

    #pragma unroll
    for (int mi = 0; mi < 4; ++mi) {
        const int row0 = mb + wr + mi * 16 + l4 * 4;
        #pragma unroll
        for (int ni = 0; ni < 4; ++ni) {
            const int colg = nb + wc + ni * 16 + l15;
            const float bv = biascat[colg];
            float v[4];
            #pragma unroll
            for (int r = 0; r < 4; ++r) v[r] = acc[mi][ni][r] + bv;

            if (which == 0) {
                if (by < 4) {
                    #pragma unroll
                    for (int r = 0; r < 4; ++r) {
                        outF[(size_t)(row0 + r) * 512 + colg] = v[r];
                        outB0[(size_t)(row0 + r) * 512 + colg] = f2bf(v[r]);
                    }
                } else if (by < 8) {
                    const int c2 = colg - 512;
                    #pragma unroll
                    for (int r = 0; r < 4; ++r)
                        outB1[(size_t)(row0 + r) * 512 + c2] = f2bf(v[r]);
                } else {
                    const int cloc = colg - 1024, i2 = cloc & 31, h2 = cloc >> 5;
                    const float pbv = biascat[colg ^ 16];
                    const bool lo = (ni & 1) == 0;
                    #pragma unroll
                    for (int r = 0; r < 4; ++r) {
                        float vp = acc[mi][ni ^ 1][r] + pbv;
                        int t = (row0 + r) & 2047;
                        float cc_ = cs[t * 16 + (i2 & 15)], ss_ = sn[t * 16 + (i2 & 15)];
                        float o = lo ? (v[r] * cc_ - vp * ss_) : (v[r] * cc_ + vp * ss_);
                        outRope[(size_t)(row0 + r) * 512 + cloc] = o;
                        outB0k[(size_t)(row0 + r) * 2048 + h2 * 128 + 96 + i2] = f2bf(o);
                    }
                }
            } else if (which == 1) {
                const int ocol = (colg / 96) * 128 + colg % 96;
                #pragma unroll
                for (int r = 0; r < 4; ++r)
                    outB0[(size_t)(row0 + r) * 2048 + ocol] = f2bf(v[r]);
            } else if (which == 2) {
                if (by < 12) {
                    const int ocol = (colg / 96) * 128 + colg % 96;
                    #pragma unroll
                    for (int r = 0; r < 4; ++r)
                        outB0[(size_t)(row0 + r) * 2048 + ocol] = f2bf(v[r]);
                } else {
                    const int cloc = colg - 1536, i2 = cloc & 31, h2 = cloc >> 5;
                    const float pbv = biascat[colg ^ 16];
                    const bool lo = (ni & 1) == 0;
                    #pragma unroll
                    for (int r = 0; r < 4; ++r) {
                        float vp = acc[mi][ni ^ 1][r] + pbv;
                        int t = (row0 + r) & 2047;
                        float cc_ = cs[t * 16 + (i2 & 15)], ss_ = sn[t * 16 + (i2 & 15)];
                        float o = lo ? (v[r] * cc_ - vp * ss_) : (v[r] * cc_ + vp * ss_);
                        outB0[(size_t)(row0 + r) * 2048 + h2 * 128 + 96 + i2] = f2bf(o);
                    }
                }
            } else {
                #pragma unroll
                for (int r = 0; r < 4; ++r)
                    outF[(size_t)(row0 + r) * 2048 + colg] = v[r];
            }
        }
    }
}

// ---------- flash attention (R6/R10 structure, frozen) ----------
__global__ __launch_bounds__(256, 2) void attn_kernel(const unsigned short* __restrict__ Q,
                                                      const unsigned short* __restrict__ Kb,
                                                      const unsigned short* __restrict__ Vtg,
                                                      unsigned short* __restrict__ O) {
    __shared__ __align__(16) unsigned short Ks[2][64 * 128];  // [key][d ^ ((key&7)<<3)]
    __shared__ __align__(16) unsigned short Vs[2][128 * 64];  // [d][k ^ ((d&7)<<3)]

    const int tid = threadIdx.x, w = tid >> 6, lane = tid & 63;
    const int l31 = lane & 31, hi = lane >> 5;
    const int bid = blockIdx.x;
    const int logical = (bid & 7) * 64 + (bid >> 3);
    const int bh = logical >> 4, b = bh >> 4, h = bh & 15;
    const int qt = (logical & 15) * 128 + w * 32;
    const int qrow = qt + l31;
    const float sl2e = 0.08838834764831845f * 1.4426950408889634f;  // scale*log2e

    bf16x8 qf[8];
    const unsigned short* qptr = Q + (size_t)(b * 2048 + qrow) * 2048 + h * 128 + hi * 8;
    #pragma unroll
    for (int s = 0; s < 8; ++s) qf[s] = *(const bf16x8*)(qptr + s * 16);

    f32x16 acc[4] = {};
    float m_run = -1e30f, l_run = 0.0f;

    const int kl15 = lane >> 4, kd0 = lane & 15;
    const int vr = lane >> 3, vk = lane & 7;

    auto STAGE = [&](int buf, int kt) {
        #pragma unroll
        for (int i = 0; i < 4; ++i) {
            int c = w * 4 + i;
            int key = c * 4 + kl15;
            int d0 = (kd0 * 8) ^ ((key & 7) << 3);
            gload16(Kb + (size_t)(b * 2048 + kt + key) * 2048 + h * 128 + d0, &Ks[buf][c * 512]);
            int dv = c * 8 + vr;
            int k0 = (vk * 8) ^ ((dv & 7) << 3);
            gload16(Vtg + (size_t)(h * 128 + dv) * 4096 + b * 2048 + kt + k0, &Vs[buf][c * 512]);
        }
    };

    STAGE(0, 0);

    for (int t = 0; t < 32; ++t) {
        const int buf = t & 1;
        if (t < 31) {
            STAGE(buf ^ 1, (t + 1) * 64);
            asm volatile("s_waitcnt vmcnt(8)" ::: "memory");
        } else {
            asm volatile("s_waitcnt vmcnt(0)" ::: "memory");
        }
        __builtin_amdgcn_sched_barrier(0);
        __builtin_amdgcn_s_barrier();
        __builtin_amdgcn_sched_barrier(0);

        #pragma unroll
        for (int g = 0; g < 2; ++g) {
            const int key = g * 32 + l31;
            const unsigned short* kbase = &Ks[buf][key * 128];
            const int ksw = (key & 7) << 3;
            f32x16 sc = {};
            __builtin_amdgcn_s_setprio(1);
            #pragma unroll
            for (int s = 0; s < 8; ++s) {
                bf16x8 kf = *(const bf16x8*)(kbase + ((s * 16 + hi * 8) ^ ksw));
                sc = __builtin_amdgcn_mfma_f32_32x32x16_bf16(kf, qf[s], sc, 0, 0, 0);
            }
            __builtin_amdgcn_s_setprio(0);

            float t0 = fmaxf(sc[0], sc[1]),  t1 = fmaxf(sc[2], sc[3]);
            float t2 = fmaxf(sc[4], sc[5]),  t3 = fmaxf(sc[6], sc[7]);
            float t4 = fmaxf(sc[8], sc[9]),  t5 = fmaxf(sc[10], sc[11]);
            float t6 = fmaxf(sc[12], sc[13]), t7 = fmaxf(sc[14], sc[15]);
            float pm = fmaxf(fmaxf(fmaxf(t0, t1), fmaxf(t2, t3)),
                             fmaxf(fmaxf(t4, t5), fmaxf(t6, t7)));
            pm = fmaxf(pm, __shfl_xor(pm, 32, 64));

            if (__any(pm > m_run + 90.51f)) {
                float mn = fmaxf(m_run, pm);
                float f = exp2a((m_run - mn) * sl2e);
                m_run = mn;
                l_run *= f;
                #pragma unroll
                for (int dg = 0; dg < 4; ++dg)
                    #pragma unroll
                    for (int i = 0; i < 16; ++i) acc[dg][i] *= f;
            }
            const float mexp2 = m_run * sl2e;

            float e[16];
            #pragma unroll
            for (int j = 0; j < 16; ++j)
                e[j] = exp2a(fmaf(sc[j], sl2e, -mexp2));
            float a0 = e[0] + e[1], a1 = e[2] + e[3], a2 = e[4] + e[5], a3 = e[6] + e[7];
            float a4 = e[8] + e[9], a5 = e[10] + e[11], a6 = e[12] + e[13], a7 = e[14] + e[15];
            l_run += ((a0 + a1) + (a2 + a3)) + ((a4 + a5) + (a6 + a7));

            #pragma unroll
            for (int s2 = 0; s2 < 2; ++s2) {
                unsigned X0 = cvtpk_bf16(e[s2 * 8 + 0], e[s2 * 8 + 1]);
                unsigned X1 = cvtpk_bf16(e[s2 * 8 + 2], e[s2 * 8 + 3]);
                unsigned Y0 = cvtpk_bf16(e[s2 * 8 + 4], e[s2 * 8 + 5]);
                unsigned Y1 = cvtpk_bf16(e[s2 * 8 + 6], e[s2 * 8 + 7]);
                pl32swap(X0, Y0);
                pl32swap(X1, Y1);
                union { unsigned u[4]; bf16x8 v; } pf;
                pf.u[0] = X0; pf.u[1] = X1; pf.u[2] = Y0; pf.u[3] = Y1;

                const int kofs = g * 32 + s2 * 16 + hi * 8;
                __builtin_amdgcn_s_setprio(1);
                #pragma unroll
                for (int dg = 0; dg < 4; ++dg) {
                    const int d = dg * 32 + l31;
                    bf16x8 vf = *(const bf16x8*)(&Vs[buf][d * 64 + (kofs ^ ((d & 7) << 3))]);
                    acc[dg] = __builtin_amdgcn_mfma_f32_32x32x16_bf16(vf, pf.v, acc[dg], 0, 0, 0);
                }
                __builtin_amdgcn_s_setprio(0);
            }
        }
        __builtin_amdgcn_s_barrier();
    }

    l_run += __shfl_xor(l_run, 32, 64);
    const float inv = 1.0f / l_run;
    unsigned short* obase = O + (size_t)(b * 2048 + qrow) * 2048 + h * 128;
    #pragma unroll
    for (int dg = 0; dg < 4; ++dg)
        #pragma unroll
        for (int k = 0; k < 4; ++k) {
            ushort4 pv;
            pv.x = f2bf(acc[dg][4 * k + 0] * inv);
            pv.y = f2bf(acc[dg][4 * k + 1] * inv);
            pv.z = f2bf(acc[dg][4 * k + 2] * inv);
            pv.w = f2bf(acc[dg][4 * k + 3] * inv);
            *(ushort4*)(obase + dg * 32 + k * 8 + hi * 4) = pv;
        }
}

extern "C" void kernel_launch(void* const* d_in, const int* in_sizes, int n_in,
                              void* d_out, int out_size, void* d_ws, size_t ws_size,
                              hipStream_t stream) {
    (void)in_sizes; (void)n_in; (void)out_size; (void)ws_size;

    const float* input  = (const float*)d_in[0];
    const float* Wdkv_w = (const float*)d_in[3];
    const float* Wdkv_b = (const float*)d_in[4];
    const float* Wdq_w  = (const float*)d_in[5];
    const float* Wdq_b  = (const float*)d_in[6];
    const float* Wuk_w  = (const float*)d_in[7];
    const float* Wuk_b  = (const float*)d_in[8];
    const float* Wuv_w  = (const float*)d_in[9];
    const float* Wuv_b  = (const float*)d_in[10];
    const float* Wuq_w  = (const float*)d_in[11];
    const float* Wuq_b  = (const float*)d_in[12];
    const float* Wqr_w  = (const float*)d_in[13];
    const float* Wqr_b  = (const float*)d_in[14];
    const float* Wkr_w  = (const float*)d_in[15];
    const float* Wkr_b  = (const float*)d_in[16];
    const float* Wo_w   = (const float*)d_in[17];
    const float* Wo_b   = (const float*)d_in[18];

    float* out_main = (float*)d_out;                       // [4096][2048]
    float* out_ckv  = out_main + (size_t)NROWS * DM;       // [4096][512]
    float* out_krot = out_ckv + (size_t)NROWS * LAT;       // [4096][512]

    char* p = (char*)d_ws;
    auto alloc = [&](size_t bytes) { char* r = p; p += (bytes + 255) & ~(size_t)255; return r; };
    unsigned short* x_bf  = (unsigned short*)alloc((size_t)NROWS * DM * 2);
    unsigned short* w1_t  = (unsigned short*)alloc((size_t)1536 * DM * 2);   // [dkv|dq|kr] x 2048
    unsigned short* w2_t  = (unsigned short*)alloc((size_t)3584 * LAT * 2);  // [uk|uv] x 512
    unsigned short* w3_t  = (unsigned short*)alloc((size_t)2048 * LAT * 2);  // [uq|qr] x 512
    unsigned short* w4_t  = (unsigned short*)alloc((size_t)DM * DM * 2);     // wo
    unsigned short* ckv_bf = (unsigned short*)alloc((size_t)NROWS * LAT * 2);
    unsigned short* cq_bf  = (unsigned short*)alloc((size_t)NROWS * LAT * 2);
    unsigned short* q_bf   = (unsigned short*)alloc((size_t)NROWS * DM * 2);
    unsigned short* k_bf   = (unsigned short*)alloc((size_t)NROWS * DM * 2);
    unsigned short* vt_g   = (unsigned short*)alloc((size_t)DM * NROWS * 2); // V^T [2048][4096]
    unsigned short* ao_bf  = (unsigned short*)alloc((size_t)NROWS * DM * 2);
    float* cos_t = (float*)alloc((size_t)2048 * 16 * 4);
    float* sin_t = (float*)alloc((size_t)2048 * 16 * 4);
    float* bc1 = (float*)alloc(1536 * 4);
    float* bc2 = (float*)alloc(3584 * 4);
    float* bc3 = (float*)alloc(2048 * 4);
    float* bc4 = (float*)alloc(2048 * 4);

    // ---- single prep dispatch ----
    PrepParams P;
    const float* tsrc[8] = {Wdkv_w, Wdq_w, Wkr_w, Wuk_w, Wuv_w, Wuq_w, Wqr_w, Wo_w};
    unsigned short* tdst[8] = {w1_t, w1_t + 512 * 2048, w1_t + 1024 * 2048,
                               w2_t, w2_t + 1536 * 512, w3_t, w3_t + 1536 * 512, w4_t};
    int tK[8] = {2048, 2048, 2048, 512, 512, 512, 512, 2048};
    int tN[8] = {512, 512, 512, 1536, 2048, 1536, 512, 2048};
    int tstart[8] = {0, 1024, 2048, 3072, 3840, 4864, 5632, 5888};
    const float* bsrc[8] = {Wdkv_b, Wdq_b, Wkr_b, Wuk_b, Wuv_b, Wuq_b, Wqr_b, Wo_b};
    float* bdst[8] = {bc1, bc1 + 512, bc1 + 1024, bc2, bc2 + 1536, bc3, bc3 + 1536, bc4};
    int blen[8] = {512, 512, 512, 1536, 2048, 1536, 512, 2048};
    for (int i = 0; i < 8; ++i) {
        P.tsrc[i] = tsrc[i]; P.tdst[i] = tdst[i]; P.tK[i] = tK[i]; P.tN[i] = tN[i];
        P.tstart[i] = tstart[i]; P.bsrc[i] = bsrc[i]; P.bdst[i] = bdst[i]; P.blen[i] = blen[i];
    }
    P.input = input; P.xbf = x_bf; P.cs = cos_t; P.sn = sin_t;
    prep_kernel<<<PREP_B_END, 256, 0, stream>>>(P);

    // G1: x @ [Wdkv|Wdq|Wkr] -> c_kv(f32+bf16), c_q(bf16), k_rot(rope: f32 out + k cols 96..127)
    gemm_fused_kernel<<<dim3(32, 12), 256, 0, stream>>>(x_bf, w1_t, bc1, 2048, 0,
                                                        out_ckv, ckv_bf, cq_bf, k_bf, out_krot, cos_t, sin_t);
    // G2: ckv @ [Wuk|Wuv] -> k_base(remap into k_bf), V^T (LDS-bounce coalesced)
    gemm_fused_kernel<<<dim3(32, 28), 256, 0, stream>>>(ckv_bf, w2_t, bc2, 512, 1,
                                                        nullptr, k_bf, vt_g, nullptr, nullptr, nullptr, nullptr);
    // G3: cq @ [Wuq|Wqr] -> q_base(remap) + q_rot(rope) into q_bf
    gemm_fused_kernel<<<dim3(32, 16), 256, 0, stream>>>(cq_bf, w3_t, bc3, 512, 2,
                                                        nullptr, q_bf, nullptr, nullptr, nullptr, cos_t, sin_t);

    // attention (1-D grid, XCD-swizzled)
    attn_kernel<<<512, 256, 0, stream>>>(q_bf, k_bf, vt_g, ao_bf);

    // G4: output projection
    gemm_fused_kernel<<<dim3(32, 16), 256, 0, stream>>>(ao_bf, w4_t, bc4, 2048, 3,
                                                        out_main, nullptr, nullptr, nullptr, nullptr, nullptr, nullptr);
}